// Round 7
// baseline (347.961 us; speedup 1.0000x reference)
//
#include <hip/hip_runtime.h>
#include <hip/hip_bf16.h>

typedef __attribute__((ext_vector_type(8))) short short8;
typedef __attribute__((ext_vector_type(4))) short short4b;
typedef __attribute__((ext_vector_type(4))) float f32x4;
typedef __attribute__((ext_vector_type(4))) int   i32x4;
typedef __attribute__((ext_vector_type(4))) unsigned int u32x4;

#define S_LEN 2048
#define DIM   64
#define NB    32
#define BR    64
#define BC    64
#define NKT   (S_LEN / BC)   // 32

#define KP  72   // K/Vt row pitch in shorts (144B, 16B-aligned rows)
#define BP  33   // fallback bits row pitch in u64
#define AP  68   // fallback attn-bounce pitch in floats

__device__ __forceinline__ short f2bf(float f) {
    __hip_bfloat16 h = __float2bfloat16(f);
    return __builtin_bit_cast(short, h);
}

// raw barrier (NO vmcnt drain) — publishes nothing
__device__ __forceinline__ void barrier_raw() {
    __builtin_amdgcn_sched_barrier(0);
    __builtin_amdgcn_s_barrier();
    __builtin_amdgcn_sched_barrier(0);
}
// publish LDS writes, then barrier (still NO vmcnt drain)
__device__ __forceinline__ void barrier_pub() {
    __builtin_amdgcn_sched_barrier(0);
    asm volatile("s_waitcnt lgkmcnt(0)" ::: "memory");
    __builtin_amdgcn_s_barrier();
    __builtin_amdgcn_sched_barrier(0);
}

// ============================ pre-pass kernels ============================

__global__ __launch_bounds__(256)
void conv_k_kernel(const float* __restrict__ k, short* __restrict__ kbf)
{
    size_t idx = ((size_t)blockIdx.x * 256 + threadIdx.x) * 8;
    const float* p = k + idx;
    float4 a = *(const float4*)p;
    float4 c = *(const float4*)(p + 4);
    short8 f;
    f[0]=f2bf(a.x); f[1]=f2bf(a.y); f[2]=f2bf(a.z); f[3]=f2bf(a.w);
    f[4]=f2bf(c.x); f[5]=f2bf(c.y); f[6]=f2bf(c.z); f[7]=f2bf(c.w);
    *(short8*)(kbf + idx) = f;
}

// V -> bf16, transposed, with sigma column-permutation within each 64-tile:
// vtb[b][d][tile][k] = V[b][tile*64 + sigma(k)][d],
// sigma(k) = (k&32) | 16*((k>>2)&1) | ((k>>1)&12) | (k&3)
__global__ __launch_bounds__(256)
void conv_vt_kernel(const float* __restrict__ v, short* __restrict__ vtb)
{
    __shared__ float tile[64][65];
    const int t  = threadIdx.x;
    const int b  = blockIdx.x >> 5;
    const int j0 = (blockIdx.x & 31) * 64;

    #pragma unroll
    for (int p = 0; p < 4; ++p) {
        int j = (t >> 4) + p * 16;
        int d = (t & 15) * 4;
        float4 x = *(const float4*)(v + ((size_t)(b * S_LEN + j0 + j) * DIM + d));
        tile[j][d+0]=x.x; tile[j][d+1]=x.y; tile[j][d+2]=x.z; tile[j][d+3]=x.w;
    }
    __syncthreads();
    #pragma unroll
    for (int p = 0; p < 4; ++p) {
        int d  = (t >> 4) + p * 16;
        int k4 = (t & 15) * 4;
        int s0 = (k4 & 32) | (((k4 >> 2) & 1) << 4) | ((k4 >> 1) & 12);
        short4b s4;
        s4[0]=f2bf(tile[s0+0][d]); s4[1]=f2bf(tile[s0+1][d]);
        s4[2]=f2bf(tile[s0+2][d]); s4[3]=f2bf(tile[s0+3][d]);
        *(short4b*)(vtb + ((size_t)(b * DIM + d) * S_LEN + j0 + k4)) = s4;
    }
}

// ============================ main kernel ============================
// Swapped-QK (lane-local softmax), full-line mask loads / attn stores,
// raw barriers (no vmcnt drain) + depth-2 mask prefetch.

__global__ __launch_bounds__(256, 4)
void sdpa_v7(const float* __restrict__ q, const int* __restrict__ mask,
             const short* __restrict__ kbf, const short* __restrict__ vtb,
             float* __restrict__ out, float* __restrict__ attn)
{
    __shared__ __align__(16) short Klds[BR * KP];        // 9.2 KB
    __shared__ __align__(16) short Vtlds[DIM * KP];      // 9.2 KB
    __shared__ unsigned short Blds[4 * NKT * 64];        // 16 KB [wv][kt][lane]

    const int t  = threadIdx.x;
    const int l  = t & 63;
    const int wv = t >> 6;
    const int lg = l >> 4;
    const int ll = l & 15;

    // XCD swizzle: batches 4x..4x+3 -> XCD x (K+Vt ~2MB fits its L2)
    const int bx  = blockIdx.x;
    const int kk  = bx >> 3;
    const int b   = (bx & 7) * 4 + (kk >> 5);
    const int i0  = (kk & 31) * BR;

    const float LOG2E_T = 0.18033688011112042f;   // log2(e)/8

    // staging map: thread t stages LDS row krow (16 shorts at kcol)
    const int krow = t >> 2;
    const int kcol = (t & 3) * 16;
    const short* const kgp = kbf + ((size_t)b * S_LEN + krow) * DIM + kcol;   // + kt*BC*DIM
    const short* const vgp = vtb + ((size_t)b * DIM + krow) * S_LEN + kcol;   // + kt*BC
    // mask: lane reads its own q-row, cols kt*BC + 16*jt + 4*lg (+0..3)
    const int* const mgp = mask + (size_t)(b * S_LEN + i0 + 16 * wv + ll) * S_LEN + 4 * lg;

    // ---- Q fragments (B-operand: col=i=ll, k=d=s*32+lg*8+m) ----
    short8 qf[2];
    {
        const float* qrow = q + ((size_t)(b * S_LEN + i0 + 16 * wv + ll) * DIM);
        #pragma unroll
        for (int s = 0; s < 2; ++s) {
            const float* p = qrow + s * 32 + lg * 8;
            float4 a = *(const float4*)p;
            float4 c = *(const float4*)(p + 4);
            short8 f;
            f[0]=f2bf(a.x); f[1]=f2bf(a.y); f[2]=f2bf(a.z); f[3]=f2bf(a.w);
            f[4]=f2bf(c.x); f[5]=f2bf(c.y); f[6]=f2bf(c.z); f[7]=f2bf(c.w);
            qf[s] = f;
        }
    }

    // ---- prologue: mask tiles 0,1 in flight (depth 2) + K tile 0 ----
    i32x4 mA[4], mB[4];
    #pragma unroll
    for (int jt = 0; jt < 4; ++jt)
        mA[jt] = __builtin_nontemporal_load((const i32x4*)(mgp + 16 * jt));
    #pragma unroll
    for (int jt = 0; jt < 4; ++jt)
        mB[jt] = __builtin_nontemporal_load((const i32x4*)(mgp + BC + 16 * jt));
    short8 kA0 = *(const short8*)(kgp);
    short8 kA1 = *(const short8*)(kgp + 8);

    float rs = 0.f;

    // ================= Phase 1: rowsums + bit-pack =================
    for (int o = 0; o < 4; ++o) {
        #pragma unroll
        for (int u = 0; u < 8; ++u) {
            const int kt = 8 * o + u;
            i32x4 (&cur)[4] = (u & 1) ? mB : mA;   // static after unroll

            // pack current tile's 16 mask bits (counted vmcnt wait: issued 2 iters ago)
            unsigned int w = 0;
            #pragma unroll
            for (int jt = 0; jt < 4; ++jt)
                #pragma unroll
                for (int r = 0; r < 4; ++r)
                    w |= (cur[jt][r] != 0 ? 1u : 0u) << (jt * 4 + r);
            Blds[(wv * NKT + kt) * 64 + l] = (unsigned short)w;

            barrier_raw();                          // all waves done reading Klds(kt-1)
            *(short8*)&Klds[krow * KP + kcol]     = kA0;
            *(short8*)&Klds[krow * KP + kcol + 8] = kA1;
            // issue K(kt+1) and mask(kt+2): stay in flight across barriers
            {
                const int ktn = (kt < NKT - 1) ? kt + 1 : kt;
                kA0 = *(const short8*)(kgp + (size_t)ktn * BC * DIM);
                kA1 = *(const short8*)(kgp + (size_t)ktn * BC * DIM + 8);
            }
            {
                const int kt2 = (kt < NKT - 2) ? kt + 2 : kt;
                const int* mp = mgp + (size_t)kt2 * BC;
                #pragma unroll
                for (int jt = 0; jt < 4; ++jt)
                    cur[jt] = __builtin_nontemporal_load((const i32x4*)(mp + 16 * jt));
            }
            barrier_pub();                          // Klds(kt) visible

            // S^T tile: C[j=16jt+4lg+r][i=ll]
            #pragma unroll
            for (int jt = 0; jt < 4; ++jt) {
                short8 kb0 = *(short8*)&Klds[(jt * 16 + ll) * KP + lg * 8];
                short8 kb1 = *(short8*)&Klds[(jt * 16 + ll) * KP + 32 + lg * 8];
                f32x4 c = {0.f, 0.f, 0.f, 0.f};
                c = __builtin_amdgcn_mfma_f32_16x16x32_bf16(kb0, qf[0], c, 0, 0, 0);
                c = __builtin_amdgcn_mfma_f32_16x16x32_bf16(kb1, qf[1], c, 0, 0, 0);
                #pragma unroll
                for (int r = 0; r < 4; ++r) {
                    unsigned int bit = (w >> (jt * 4 + r)) & 1u;
                    rs += bit ? 0.f : __builtin_amdgcn_exp2f(c[r] * LOG2E_T);
                }
            }
        }
    }

    // phase-2 tile-0 prefetch before the reduce (covers latency)
    kA0 = *(const short8*)(kgp);
    kA1 = *(const short8*)(kgp + 8);
    short8 vA0 = *(const short8*)(vgp);
    short8 vA1 = *(const short8*)(vgp + 8);

    rs += __shfl_xor(rs, 16);
    rs += __shfl_xor(rs, 32);
    const float inv = 1.0f / rs;

    // ================= Phase 2: attn write + PV =================
    f32x4 oacc[4];
    #pragma unroll
    for (int dt = 0; dt < 4; ++dt) oacc[dt] = (f32x4){0.f, 0.f, 0.f, 0.f};

    float* const arow0 = attn + (size_t)(b * S_LEN + i0 + 16 * wv + ll) * S_LEN + 4 * lg;

    for (int o = 0; o < 4; ++o) {
        #pragma unroll
        for (int u = 0; u < 8; ++u) {
            const int kt = 8 * o + u;
            const int j0 = kt * BC;

            barrier_raw();                          // all waves done reading prev K/V
            *(short8*)&Klds[krow * KP + kcol]      = kA0;
            *(short8*)&Klds[krow * KP + kcol + 8]  = kA1;
            *(short8*)&Vtlds[krow * KP + kcol]     = vA0;
            *(short8*)&Vtlds[krow * KP + kcol + 8] = vA1;
            {
                const int ktn = (kt < NKT - 1) ? kt + 1 : kt;
                kA0 = *(const short8*)(kgp + (size_t)ktn * BC * DIM);
                kA1 = *(const short8*)(kgp + (size_t)ktn * BC * DIM + 8);
                vA0 = *(const short8*)(vgp + (size_t)ktn * BC);
                vA1 = *(const short8*)(vgp + (size_t)ktn * BC + 8);
            }
            barrier_pub();                          // K/Vt(kt) visible

            unsigned int w = Blds[(wv * NKT + kt) * 64 + l];

            // QK^T -> normalized P, lane-local: pn[jt][r] = P[i=ll][j0+16jt+4lg+r]
            f32x4 pn[4];
            #pragma unroll
            for (int jt = 0; jt < 4; ++jt) {
                short8 kb0 = *(short8*)&Klds[(jt * 16 + ll) * KP + lg * 8];
                short8 kb1 = *(short8*)&Klds[(jt * 16 + ll) * KP + 32 + lg * 8];
                f32x4 c = {0.f, 0.f, 0.f, 0.f};
                c = __builtin_amdgcn_mfma_f32_16x16x32_bf16(kb0, qf[0], c, 0, 0, 0);
                c = __builtin_amdgcn_mfma_f32_16x16x32_bf16(kb1, qf[1], c, 0, 0, 0);
                #pragma unroll
                for (int r = 0; r < 4; ++r) {
                    unsigned int bit = (w >> (jt * 4 + r)) & 1u;
                    pn[jt][r] = bit ? 0.f : __builtin_amdgcn_exp2f(c[r] * LOG2E_T) * inv;
                }
            }

            // full-line attn stores: per row, 4 lg-lanes cover one 64B line per jt
            {
                float* ar = arow0 + j0;
                __builtin_nontemporal_store(pn[0], (f32x4*)(ar + 0));
                __builtin_nontemporal_store(pn[1], (f32x4*)(ar + 16));
                __builtin_nontemporal_store(pn[2], (f32x4*)(ar + 32));
                __builtin_nontemporal_store(pn[3], (f32x4*)(ar + 48));
            }

            // lane-local bf16 pack -> PV B-fragments (sigma baked into Vt prepass)
            unsigned int p00 = (unsigned int)(unsigned short)f2bf(pn[0][0]) |
                               ((unsigned int)(unsigned short)f2bf(pn[0][1]) << 16);
            unsigned int p01 = (unsigned int)(unsigned short)f2bf(pn[0][2]) |
                               ((unsigned int)(unsigned short)f2bf(pn[0][3]) << 16);
            unsigned int p10 = (unsigned int)(unsigned short)f2bf(pn[1][0]) |
                               ((unsigned int)(unsigned short)f2bf(pn[1][1]) << 16);
            unsigned int p11 = (unsigned int)(unsigned short)f2bf(pn[1][2]) |
                               ((unsigned int)(unsigned short)f2bf(pn[1][3]) << 16);
            unsigned int p20 = (unsigned int)(unsigned short)f2bf(pn[2][0]) |
                               ((unsigned int)(unsigned short)f2bf(pn[2][1]) << 16);
            unsigned int p21 = (unsigned int)(unsigned short)f2bf(pn[2][2]) |
                               ((unsigned int)(unsigned short)f2bf(pn[2][3]) << 16);
            unsigned int p30 = (unsigned int)(unsigned short)f2bf(pn[3][0]) |
                               ((unsigned int)(unsigned short)f2bf(pn[3][1]) << 16);
            unsigned int p31 = (unsigned int)(unsigned short)f2bf(pn[3][2]) |
                               ((unsigned int)(unsigned short)f2bf(pn[3][3]) << 16);
            u32x4 pv0 = {p00, p01, p10, p11};
            u32x4 pv1 = {p20, p21, p30, p31};
            short8 paf0 = __builtin_bit_cast(short8, pv0);
            short8 paf1 = __builtin_bit_cast(short8, pv1);

            // PV: O^T[d'][i] accumulate
            #pragma unroll
            for (int dt = 0; dt < 4; ++dt) {
                short8 vb0 = *(short8*)&Vtlds[(dt * 16 + ll) * KP + lg * 8];
                short8 vb1 = *(short8*)&Vtlds[(dt * 16 + ll) * KP + 32 + lg * 8];
                oacc[dt] = __builtin_amdgcn_mfma_f32_16x16x32_bf16(vb0, paf0, oacc[dt], 0, 0, 0);
                oacc[dt] = __builtin_amdgcn_mfma_f32_16x16x32_bf16(vb1, paf1, oacc[dt], 0, 0, 0);
            }
        }
    }

    // out: lane holds O[i=ll][d = dt*16 + 4lg + r] -> full-line f32x4 stores
    {
        float* orow = out + (size_t)(b * S_LEN + i0 + 16 * wv + ll) * DIM + 4 * lg;
        #pragma unroll
        for (int dt = 0; dt < 4; ++dt)
            *(f32x4*)(orow + dt * 16) = oacc[dt];
    }
}

// ============================ fallback (proven R2 kernel) ============================

__global__ __launch_bounds__(256, 3)
void sdpa_fb(const float* __restrict__ q, const float* __restrict__ k,
             const float* __restrict__ v, const int* __restrict__ mask,
             float* __restrict__ out, float* __restrict__ attn)
{
    __shared__ __align__(16) short Klds[BR * KP];
    __shared__ __align__(16) short Vtlds[DIM * KP];
    __shared__ __align__(16) unsigned long long Bits[BR * BP];
    __shared__ __align__(16) float Albs[BR * AP];

    const int t  = threadIdx.x;
    const int l  = t & 63;
    const int wv = t >> 6;
    const int lg = l >> 4;
    const int ll = l & 15;

    const int wg = blockIdx.x;
    const int b  = wg >> 5;
    const int i0 = (wg & 31) * BR;

    const float LOG2E_T = 0.18033688011112042f;

    short8 qf[2];
    {
        const float* qrow = q + ((size_t)(b * S_LEN + i0 + 16 * wv + ll) * DIM);
        #pragma unroll
        for (int s = 0; s < 2; ++s) {
            const float* p = qrow + s * 32 + lg * 8;
            float4 a = *(const float4*)p;
            float4 c = *(const float4*)(p + 4);
            short8 f;
            f[0]=f2bf(a.x); f[1]=f2bf(a.y); f[2]=f2bf(a.z); f[3]=f2bf(a.w);
            f[4]=f2bf(c.x); f[5]=f2bf(c.y); f[6]=f2bf(c.z); f[7]=f2bf(c.w);
            qf[s] = f;
        }
    }

    float rs[4] = {0.f, 0.f, 0.f, 0.f};

    for (int kt = 0; kt < NKT; ++kt) {
        const int j0 = kt * BC;
        #pragma unroll
        for (int p = 0; p < 4; ++p) {
            int row = (t >> 4) + p * 16;
            int dd  = (t & 15) * 4;
            float4 kv4 = *(const float4*)(k + ((size_t)(b * S_LEN + j0 + row) * DIM + dd));
            short4b s4;
            s4[0]=f2bf(kv4.x); s4[1]=f2bf(kv4.y); s4[2]=f2bf(kv4.z); s4[3]=f2bf(kv4.w);
            *(short4b*)&Klds[row * KP + dd] = s4;
        }
        {
            const int* mrow = mask + (size_t)(b * S_LEN + i0 + 16 * wv) * S_LEN + j0 + l;
            int mv[16];
            #pragma unroll
            for (int r = 0; r < 16; ++r)
                mv[r] = __builtin_nontemporal_load(mrow + (size_t)r * S_LEN);
            unsigned long long myword = 0ull;
            #pragma unroll
            for (int r = 0; r < 16; ++r) {
                unsigned long long bal = __ballot(mv[r] != 0);
                if (ll == r) myword = bal;
            }
            if (l < 16) Bits[(16 * wv + l) * BP + kt] = myword;
        }
        __syncthreads();

        unsigned long long wbits[4];
        #pragma unroll
        for (int r = 0; r < 4; ++r)
            wbits[r] = Bits[(16 * wv + lg * 4 + r) * BP + kt];

        #pragma unroll
        for (int jt = 0; jt < 4; ++jt) {
            short8 b0 = *(short8*)&Klds[(jt * 16 + ll) * KP + lg * 8];
            short8 b1 = *(short8*)&Klds[(jt * 16 + ll) * KP + 32 + lg * 8];
            f32x4 c = {0.f, 0.f, 0.f, 0.f};
            c = __builtin_amdgcn_mfma_f32_16x16x32_bf16(qf[0], b0, c, 0, 0, 0);
            c = __builtin_amdgcn_mfma_f32_16x16x32_bf16(qf[1], b1, c, 0, 0, 0);
            #pragma unroll
            for (int r = 0; r < 4; ++r) {
                unsigned int bit = (unsigned int)(wbits[r] >> (jt * 16 + ll)) & 1u;
                rs[r] += bit ? 0.f : __builtin_amdgcn_exp2f(c[r] * LOG2E_T);
            }
        }
        __syncthreads();
    }

    float inv[4];
    #pragma unroll
    for (int r = 0; r < 4; ++r) {
        float s = rs[r];
        s += __shfl_xor(s, 1);
        s += __shfl_xor(s, 2);
        s += __shfl_xor(s, 4);
        s += __shfl_xor(s, 8);
        inv[r] = 1.0f / s;
    }

    f32x4 oacc[4];
    #pragma unroll
    for (int dt = 0; dt < 4; ++dt) oacc[dt] = (f32x4){0.f, 0.f, 0.f, 0.f};

    for (int kt = 0; kt < NKT; ++kt) {
        const int j0 = kt * BC;
        #pragma unroll
        for (int p = 0; p < 4; ++p) {
            int row = (t >> 4) + p * 16;
            int dd  = (t & 15) * 4;
            float4 kv4 = *(const float4*)(k + ((size_t)(b * S_LEN + j0 + row) * DIM + dd));
            short4b s4;
            s4[0]=f2bf(kv4.x); s4[1]=f2bf(kv4.y); s4[2]=f2bf(kv4.z); s4[3]=f2bf(kv4.w);
            *(short4b*)&Klds[row * KP + dd] = s4;
        }
        #pragma unroll
        for (int it = 0; it < 8; ++it) {
            int jp = (t >> 4) + (it & 1) * 16;
            int dd = (t & 15) + (it >> 1) * 16;
            const float* vp = v + ((size_t)(b * S_LEN + j0 + jp * 2) * DIM + dd);
            float v0 = vp[0];
            float v1 = vp[DIM];
            unsigned int pk = (unsigned int)(unsigned short)f2bf(v0) |
                              ((unsigned int)(unsigned short)f2bf(v1) << 16);
            *(unsigned int*)&Vtlds[dd * KP + jp * 2] = pk;
        }
        __syncthreads();

        unsigned long long wbits[4];
        #pragma unroll
        for (int r = 0; r < 4; ++r)
            wbits[r] = Bits[(16 * wv + lg * 4 + r) * BP + kt];

        #pragma unroll
        for (int jt = 0; jt < 4; ++jt) {
            short8 b0 = *(short8*)&Klds[(jt * 16 + ll) * KP + lg * 8];
            short8 b1 = *(short8*)&Klds[(jt * 16 + ll) * KP + 32 + lg * 8];
            f32x4 c = {0.f, 0.f, 0.f, 0.f};
            c = __builtin_amdgcn_mfma_f32_16x16x32_bf16(qf[0], b0, c, 0, 0, 0);
            c = __builtin_amdgcn_mfma_f32_16x16x32_bf16(qf[1], b1, c, 0, 0, 0);
            #pragma unroll
            for (int r = 0; r < 4; ++r) {
                unsigned int bit = (unsigned int)(wbits[r] >> (jt * 16 + ll)) & 1u;
                float pexp = bit ? 0.f : __builtin_amdgcn_exp2f(c[r] * LOG2E_T);
                Albs[(16 * wv + lg * 4 + r) * AP + jt * 16 + ll] = pexp * inv[r];
            }
        }

        short8 paf[2];
        #pragma unroll
        for (int s = 0; s < 2; ++s) {
            const float* ap = &Albs[(16 * wv + ll) * AP + s * 32 + lg * 8];
            float4 x = *(const float4*)ap;
            float4 y = *(const float4*)(ap + 4);
            short8 f;
            f[0]=f2bf(x.x); f[1]=f2bf(x.y); f[2]=f2bf(x.z); f[3]=f2bf(x.w);
            f[4]=f2bf(y.x); f[5]=f2bf(y.y); f[6]=f2bf(y.z); f[7]=f2bf(y.w);
            paf[s] = f;
        }

        #pragma unroll
        for (int dt = 0; dt < 4; ++dt) {
            short8 b0 = *(short8*)&Vtlds[(dt * 16 + ll) * KP + lg * 8];
            short8 b1 = *(short8*)&Vtlds[(dt * 16 + ll) * KP + 32 + lg * 8];
            oacc[dt] = __builtin_amdgcn_mfma_f32_16x16x32_bf16(paf[0], b0, oacc[dt], 0, 0, 0);
            oacc[dt] = __builtin_amdgcn_mfma_f32_16x16x32_bf16(paf[1], b1, oacc[dt], 0, 0, 0);
        }

        {
            float* abase = attn + (size_t)b * S_LEN * S_LEN;
            #pragma unroll
            for (int ps = 0; ps < 4; ++ps) {
                int row = 16 * wv + lg + ps * 4;
                f32x4 val = *(f32x4*)&Albs[row * AP + ll * 4];
                float* dst = abase + (size_t)(i0 + row) * S_LEN + j0 + ll * 4;
                __builtin_nontemporal_store(val, (f32x4*)dst);
            }
        }
        __syncthreads();
    }

    #pragma unroll
    for (int dt = 0; dt < 4; ++dt)
        #pragma unroll
        for (int r = 0; r < 4; ++r)
            out[(size_t)(b * S_LEN + i0 + 16 * wv + lg * 4 + r) * DIM + dt * 16 + ll] = oacc[dt][r];
}

extern "C" void kernel_launch(void* const* d_in, const int* in_sizes, int n_in,
                              void* d_out, int out_size, void* d_ws, size_t ws_size,
                              hipStream_t stream) {
    const float* q    = (const float*)d_in[0];
    const float* k    = (const float*)d_in[1];
    const float* v    = (const float*)d_in[2];
    const int*   mask = (const int*)d_in[3];
    float* out  = (float*)d_out;
    float* attn = out + (size_t)NB * S_LEN * DIM;

    const size_t nel = (size_t)NB * S_LEN * DIM;       // 4.19M
    const size_t ws_needed = 2 * nel * sizeof(short);  // 16.8 MB

    if (ws_size >= ws_needed) {
        short* kbf = (short*)d_ws;
        short* vtb = kbf + nel;
        conv_k_kernel<<<dim3(nel / (256 * 8)), dim3(256), 0, stream>>>(k, kbf);
        conv_vt_kernel<<<dim3(NB * 32), dim3(256), 0, stream>>>(v, vtb);
        sdpa_v7<<<dim3(NB * (S_LEN / BR)), dim3(256), 0, stream>>>(q, mask, kbf, vtb, out, attn);
    } else {
        sdpa_fb<<<dim3(NB * (S_LEN / BR)), dim3(256), 0, stream>>>(q, k, v, mask, out, attn);
    }
}

// Round 8
// 305.235 us; speedup vs baseline: 1.1400x; 1.1400x over previous
//
#include <hip/hip_runtime.h>
#include <hip/hip_bf16.h>

typedef __attribute__((ext_vector_type(8))) short short8;
typedef __attribute__((ext_vector_type(4))) short short4b;
typedef __attribute__((ext_vector_type(4))) float f32x4;

#define S_LEN 2048
#define DIM   64
#define NB    32
#define BR    64
#define BC    64
#define NKT   (S_LEN / BC)   // 32

#define KP  72   // K/Vt row pitch in shorts (144B, 16B-aligned rows)
#define BP  33   // fallback bits row pitch in u64
#define AP  68   // attn-bounce row pitch in floats (272B, 16B-aligned)

__device__ __forceinline__ short f2bf(float f) {
    __hip_bfloat16 h = __float2bfloat16(f);
    return __builtin_bit_cast(short, h);
}

// raw barrier: NO implicit vmcnt/lgkm drain
__device__ __forceinline__ void barrier_raw() {
    __builtin_amdgcn_sched_barrier(0);
    __builtin_amdgcn_s_barrier();
    __builtin_amdgcn_sched_barrier(0);
}
// publish this wave's LDS writes, then barrier (still no vmcnt drain)
__device__ __forceinline__ void barrier_pub() {
    __builtin_amdgcn_sched_barrier(0);
    asm volatile("s_waitcnt lgkmcnt(0)" ::: "memory");
    __builtin_amdgcn_s_barrier();
    __builtin_amdgcn_sched_barrier(0);
}

// ============================ pre-pass kernels ============================

__global__ __launch_bounds__(256)
void conv_k_kernel(const float* __restrict__ k, short* __restrict__ kbf)
{
    size_t idx = ((size_t)blockIdx.x * 256 + threadIdx.x) * 8;
    const float* p = k + idx;
    float4 a = *(const float4*)p;
    float4 c = *(const float4*)(p + 4);
    short8 f;
    f[0]=f2bf(a.x); f[1]=f2bf(a.y); f[2]=f2bf(a.z); f[3]=f2bf(a.w);
    f[4]=f2bf(c.x); f[5]=f2bf(c.y); f[6]=f2bf(c.z); f[7]=f2bf(c.w);
    *(short8*)(kbf + idx) = f;
}

__global__ __launch_bounds__(256)
void conv_vt_kernel(const float* __restrict__ v, short* __restrict__ vtb)
{
    __shared__ float tile[64][65];
    const int t  = threadIdx.x;
    const int b  = blockIdx.x >> 5;
    const int j0 = (blockIdx.x & 31) * 64;

    #pragma unroll
    for (int p = 0; p < 4; ++p) {
        int j = (t >> 4) + p * 16;
        int d = (t & 15) * 4;
        float4 x = *(const float4*)(v + ((size_t)(b * S_LEN + j0 + j) * DIM + d));
        tile[j][d+0]=x.x; tile[j][d+1]=x.y; tile[j][d+2]=x.z; tile[j][d+3]=x.w;
    }
    __syncthreads();
    #pragma unroll
    for (int p = 0; p < 4; ++p) {
        int d  = (t >> 4) + p * 16;
        int j4 = (t & 15) * 4;
        short4b s4;
        s4[0]=f2bf(tile[j4+0][d]); s4[1]=f2bf(tile[j4+1][d]);
        s4[2]=f2bf(tile[j4+2][d]); s4[3]=f2bf(tile[j4+3][d]);
        *(short4b*)(vtb + ((size_t)(b * DIM + d) * S_LEN + j0 + j4)) = s4;
    }
}

// ============================ main kernel (R4 + counted-vmcnt pipeline) ============================

__global__ __launch_bounds__(256, 4)
void sdpa_v8(const float* __restrict__ q, const int* __restrict__ mask,
             const short* __restrict__ kbf, const short* __restrict__ vtb,
             float* __restrict__ out, float* __restrict__ attn)
{
    __shared__ __align__(16) short Klds[BR * KP];    // 9.2 KB
    __shared__ __align__(16) short Vtlds[DIM * KP];  // 9.2 KB
    __shared__ __align__(16) float Albs[BR * AP];    // 17.4 KB => 35.8 KB total

    const int t  = threadIdx.x;
    const int l  = t & 63;
    const int wv = t >> 6;
    const int lg = l >> 4;
    const int ll = l & 15;

    // XCD swizzle: batches 4x..4x+3 -> XCD x (K+Vt ~2MB fits its L2)
    const int bx  = blockIdx.x;
    const int kk  = bx >> 3;
    const int b   = (bx & 7) * 4 + (kk >> 5);
    const int i0  = (kk & 31) * BR;

    const float LOG2E_T = 0.18033688011112042f;   // log2(e)/8

    // staging map: thread t stages LDS row krow (16 shorts at kcol)
    const int krow = t >> 2;
    const int kcol = (t & 3) * 16;
    const size_t kgbase = (size_t)(b * S_LEN + krow) * DIM + kcol;        // + kt*BC*DIM
    const size_t vgbase = (size_t)(b * DIM + krow) * S_LEN + kcol;        // + kt*BC
    const size_t mbase  = (size_t)(b * S_LEN + i0 + 16 * wv) * S_LEN + l; // + kt*BC

    // ---- Q fragments ----
    short8 qf[2];
    {
        const float* qrow = q + ((size_t)(b * S_LEN + i0 + 16 * wv + ll) * DIM);
        #pragma unroll
        for (int s = 0; s < 2; ++s) {
            const float* p = qrow + s * 32 + lg * 8;
            float4 a = *(const float4*)p;
            float4 c = *(const float4*)(p + 4);
            short8 f;
            f[0]=f2bf(a.x); f[1]=f2bf(a.y); f[2]=f2bf(a.z); f[3]=f2bf(a.w);
            f[4]=f2bf(c.x); f[5]=f2bf(c.y); f[6]=f2bf(c.z); f[7]=f2bf(c.w);
            qf[s] = f;
        }
    }

    // ---- prologue: K tile0, mask tiles 0 and 1 in flight ----
    short8 kA0 = *(const short8*)(kbf + kgbase);
    short8 kA1 = *(const short8*)(kbf + kgbase + 8);
    int mA[16], mB[16];
    #pragma unroll
    for (int r = 0; r < 16; ++r)
        mA[r] = __builtin_nontemporal_load(mask + mbase + (size_t)r * S_LEN);
    #pragma unroll
    for (int r = 0; r < 16; ++r)
        mB[r] = __builtin_nontemporal_load(mask + mbase + BC + (size_t)r * S_LEN);

    float rs[4] = {0.f, 0.f, 0.f, 0.f};
    unsigned long long w8[8];

    // ================= Phase 1: rowsums, mask bits -> registers =================
    for (int o = 0; o < 4; ++o) {
        #pragma unroll
        for (int u = 0; u < 8; ++u) {
            const int kt = 8 * o + u;
            int (&cur)[16] = (u & 1) ? mB : mA;   // u is literal after unroll

            // ballots on tile kt (loads issued ~2 iterations ago; counted wait)
            unsigned long long wb[4];
            #pragma unroll
            for (int r = 0; r < 16; ++r) {
                unsigned long long bal = __ballot(cur[r] != 0);
                if ((r >> 2) == lg) wb[r & 3] = bal;
                if (lg == o && ll == r) w8[u] = bal;
            }

            barrier_raw();     // all waves done reading Klds(kt-1)
            {
                short* kd = &Klds[krow * KP + kcol];
                *(short8*)kd = kA0;           // waits vmcnt for K loads only (oldest)
                *(short8*)(kd + 8) = kA1;
            }
            barrier_pub();     // Klds(kt) visible

            // issue next loads RIGHT AFTER the barrier: in flight across compute
            {
                const int ktn = (kt < NKT - 1) ? kt + 1 : kt;
                const short* kb = kbf + kgbase + (size_t)ktn * BC * DIM;
                kA0 = *(const short8*)kb;
                kA1 = *(const short8*)(kb + 8);
                const int kt2 = (kt < NKT - 2) ? kt + 2 : kt;
                const int* mrow = mask + mbase + (size_t)kt2 * BC;
                #pragma unroll
                for (int r = 0; r < 16; ++r)
                    cur[r] = __builtin_nontemporal_load(mrow + (size_t)r * S_LEN);
            }
            __builtin_amdgcn_sched_barrier(0);

            // compute tile kt
            #pragma unroll
            for (int jt = 0; jt < 4; ++jt) {
                short8 b0 = *(short8*)&Klds[(jt * 16 + ll) * KP + lg * 8];
                short8 b1 = *(short8*)&Klds[(jt * 16 + ll) * KP + 32 + lg * 8];
                f32x4 c = {0.f, 0.f, 0.f, 0.f};
                c = __builtin_amdgcn_mfma_f32_16x16x32_bf16(qf[0], b0, c, 0, 0, 0);
                c = __builtin_amdgcn_mfma_f32_16x16x32_bf16(qf[1], b1, c, 0, 0, 0);
                #pragma unroll
                for (int r = 0; r < 4; ++r) {
                    unsigned int bit = (unsigned int)(wb[r] >> (jt * 16 + ll)) & 1u;
                    rs[r] += bit ? 0.f : __builtin_amdgcn_exp2f(c[r] * LOG2E_T);
                }
            }
        }
    }

    // phase-2 tile-0 prefetch before the reduce (covers latency)
    kA0 = *(const short8*)(kbf + kgbase);
    kA1 = *(const short8*)(kbf + kgbase + 8);
    short8 vA0 = *(const short8*)(vtb + vgbase);
    short8 vA1 = *(const short8*)(vtb + vgbase + 8);

    float inv[4];
    #pragma unroll
    for (int r = 0; r < 4; ++r) {
        float s = rs[r];
        s += __shfl_xor(s, 1);
        s += __shfl_xor(s, 2);
        s += __shfl_xor(s, 4);
        s += __shfl_xor(s, 8);
        inv[r] = 1.0f / s;
    }

    // ================= Phase 2: attn write + PV =================
    f32x4 oacc[4];
    #pragma unroll
    for (int dt = 0; dt < 4; ++dt) oacc[dt] = (f32x4){0.f, 0.f, 0.f, 0.f};

    float* const abase = attn + (size_t)b * S_LEN * S_LEN;

    for (int o = 0; o < 4; ++o) {
        #pragma unroll
        for (int u = 0; u < 8; ++u) {
            const int kt = 8 * o + u;
            const int j0 = kt * BC;

            barrier_raw();     // all waves done reading K/Vt(kt-1)
            {
                short* kd = &Klds[krow * KP + kcol];
                *(short8*)kd = kA0;
                *(short8*)(kd + 8) = kA1;
                short* vd = &Vtlds[krow * KP + kcol];
                *(short8*)vd = vA0;
                *(short8*)(vd + 8) = vA1;
            }
            barrier_pub();     // K/Vt(kt) visible

            // issue next K/V right after the barrier
            {
                const int ktn = (kt < NKT - 1) ? kt + 1 : kt;
                const short* kb = kbf + kgbase + (size_t)ktn * BC * DIM;
                kA0 = *(const short8*)kb;
                kA1 = *(const short8*)(kb + 8);
                const short* vb = vtb + vgbase + (size_t)ktn * BC;
                vA0 = *(const short8*)vb;
                vA1 = *(const short8*)(vb + 8);
            }
            __builtin_amdgcn_sched_barrier(0);

            unsigned long long wb[4];
            #pragma unroll
            for (int r = 0; r < 4; ++r)
                wb[r] = __shfl(w8[u], 16 * o + lg * 4 + r);

            // QK^T -> normalized p -> Albs (wave-private rows)
            #pragma unroll
            for (int jt = 0; jt < 4; ++jt) {
                short8 b0 = *(short8*)&Klds[(jt * 16 + ll) * KP + lg * 8];
                short8 b1 = *(short8*)&Klds[(jt * 16 + ll) * KP + 32 + lg * 8];
                f32x4 c = {0.f, 0.f, 0.f, 0.f};
                c = __builtin_amdgcn_mfma_f32_16x16x32_bf16(qf[0], b0, c, 0, 0, 0);
                c = __builtin_amdgcn_mfma_f32_16x16x32_bf16(qf[1], b1, c, 0, 0, 0);
                #pragma unroll
                for (int r = 0; r < 4; ++r) {
                    unsigned int bit = (unsigned int)(wb[r] >> (jt * 16 + ll)) & 1u;
                    float pexp = bit ? 0.f : __builtin_amdgcn_exp2f(c[r] * LOG2E_T);
                    Albs[(16 * wv + lg * 4 + r) * AP + jt * 16 + ll] = pexp * inv[r];
                }
            }

            // PV A-fragments from wave-private bounce (transpose for free)
            short8 paf[2];
            #pragma unroll
            for (int s = 0; s < 2; ++s) {
                const float* ap = &Albs[(16 * wv + ll) * AP + s * 32 + lg * 8];
                float4 x = *(const float4*)ap;
                float4 y = *(const float4*)(ap + 4);
                short8 f;
                f[0]=f2bf(x.x); f[1]=f2bf(x.y); f[2]=f2bf(x.z); f[3]=f2bf(x.w);
                f[4]=f2bf(y.x); f[5]=f2bf(y.y); f[6]=f2bf(y.z); f[7]=f2bf(y.w);
                paf[s] = f;
            }

            #pragma unroll
            for (int dt = 0; dt < 4; ++dt) {
                short8 b0 = *(short8*)&Vtlds[(dt * 16 + ll) * KP + lg * 8];
                short8 b1 = *(short8*)&Vtlds[(dt * 16 + ll) * KP + 32 + lg * 8];
                oacc[dt] = __builtin_amdgcn_mfma_f32_16x16x32_bf16(paf[0], b0, oacc[dt], 0, 0, 0);
                oacc[dt] = __builtin_amdgcn_mfma_f32_16x16x32_bf16(paf[1], b1, oacc[dt], 0, 0, 0);
            }

            // coalesced attn tile store (256B contiguous per row, NT)
            #pragma unroll
            for (int ps = 0; ps < 4; ++ps) {
                int row = 16 * wv + lg + ps * 4;
                f32x4 val = *(f32x4*)&Albs[row * AP + ll * 4];
                float* dst = abase + (size_t)(i0 + row) * S_LEN + j0 + ll * 4;
                __builtin_nontemporal_store(val, (f32x4*)dst);
            }
        }
    }

    #pragma unroll
    for (int dt = 0; dt < 4; ++dt)
        #pragma unroll
        for (int r = 0; r < 4; ++r)
            out[(size_t)(b * S_LEN + i0 + 16 * wv + lg * 4 + r) * DIM + dt * 16 + ll] = oacc[dt][r];
}

// ============================ fallback (proven R2 kernel) ============================

__global__ __launch_bounds__(256, 3)
void sdpa_fb(const float* __restrict__ q, const float* __restrict__ k,
             const float* __restrict__ v, const int* __restrict__ mask,
             float* __restrict__ out, float* __restrict__ attn)
{
    __shared__ __align__(16) short Klds[BR * KP];
    __shared__ __align__(16) short Vtlds[DIM * KP];
    __shared__ __align__(16) unsigned long long Bits[BR * BP];
    __shared__ __align__(16) float Albs[BR * AP];

    const int t  = threadIdx.x;
    const int l  = t & 63;
    const int wv = t >> 6;
    const int lg = l >> 4;
    const int ll = l & 15;

    const int wg = blockIdx.x;
    const int b  = wg >> 5;
    const int i0 = (wg & 31) * BR;

    const float LOG2E_T = 0.18033688011112042f;

    short8 qf[2];
    {
        const float* qrow = q + ((size_t)(b * S_LEN + i0 + 16 * wv + ll) * DIM);
        #pragma unroll
        for (int s = 0; s < 2; ++s) {
            const float* p = qrow + s * 32 + lg * 8;
            float4 a = *(const float4*)p;
            float4 c = *(const float4*)(p + 4);
            short8 f;
            f[0]=f2bf(a.x); f[1]=f2bf(a.y); f[2]=f2bf(a.z); f[3]=f2bf(a.w);
            f[4]=f2bf(c.x); f[5]=f2bf(c.y); f[6]=f2bf(c.z); f[7]=f2bf(c.w);
            qf[s] = f;
        }
    }

    float rs[4] = {0.f, 0.f, 0.f, 0.f};

    for (int kt = 0; kt < NKT; ++kt) {
        const int j0 = kt * BC;
        #pragma unroll
        for (int p = 0; p < 4; ++p) {
            int row = (t >> 4) + p * 16;
            int dd  = (t & 15) * 4;
            float4 kv4 = *(const float4*)(k + ((size_t)(b * S_LEN + j0 + row) * DIM + dd));
            short4b s4;
            s4[0]=f2bf(kv4.x); s4[1]=f2bf(kv4.y); s4[2]=f2bf(kv4.z); s4[3]=f2bf(kv4.w);
            *(short4b*)&Klds[row * KP + dd] = s4;
        }
        {
            const int* mrow = mask + (size_t)(b * S_LEN + i0 + 16 * wv) * S_LEN + j0 + l;
            int mv[16];
            #pragma unroll
            for (int r = 0; r < 16; ++r)
                mv[r] = __builtin_nontemporal_load(mrow + (size_t)r * S_LEN);
            unsigned long long myword = 0ull;
            #pragma unroll
            for (int r = 0; r < 16; ++r) {
                unsigned long long bal = __ballot(mv[r] != 0);
                if (ll == r) myword = bal;
            }
            if (l < 16) Bits[(16 * wv + l) * BP + kt] = myword;
        }
        __syncthreads();

        unsigned long long wbits[4];
        #pragma unroll
        for (int r = 0; r < 4; ++r)
            wbits[r] = Bits[(16 * wv + lg * 4 + r) * BP + kt];

        #pragma unroll
        for (int jt = 0; jt < 4; ++jt) {
            short8 b0 = *(short8*)&Klds[(jt * 16 + ll) * KP + lg * 8];
            short8 b1 = *(short8*)&Klds[(jt * 16 + ll) * KP + 32 + lg * 8];
            f32x4 c = {0.f, 0.f, 0.f, 0.f};
            c = __builtin_amdgcn_mfma_f32_16x16x32_bf16(qf[0], b0, c, 0, 0, 0);
            c = __builtin_amdgcn_mfma_f32_16x16x32_bf16(qf[1], b1, c, 0, 0, 0);
            #pragma unroll
            for (int r = 0; r < 4; ++r) {
                unsigned int bit = (unsigned int)(wbits[r] >> (jt * 16 + ll)) & 1u;
                rs[r] += bit ? 0.f : __builtin_amdgcn_exp2f(c[r] * LOG2E_T);
            }
        }
        __syncthreads();
    }

    float inv[4];
    #pragma unroll
    for (int r = 0; r < 4; ++r) {
        float s = rs[r];
        s += __shfl_xor(s, 1);
        s += __shfl_xor(s, 2);
        s += __shfl_xor(s, 4);
        s += __shfl_xor(s, 8);
        inv[r] = 1.0f / s;
    }

    f32x4 oacc[4];
    #pragma unroll
    for (int dt = 0; dt < 4; ++dt) oacc[dt] = (f32x4){0.f, 0.f, 0.f, 0.f};

    for (int kt = 0; kt < NKT; ++kt) {
        const int j0 = kt * BC;
        #pragma unroll
        for (int p = 0; p < 4; ++p) {
            int row = (t >> 4) + p * 16;
            int dd  = (t & 15) * 4;
            float4 kv4 = *(const float4*)(k + ((size_t)(b * S_LEN + j0 + row) * DIM + dd));
            short4b s4;
            s4[0]=f2bf(kv4.x); s4[1]=f2bf(kv4.y); s4[2]=f2bf(kv4.z); s4[3]=f2bf(kv4.w);
            *(short4b*)&Klds[row * KP + dd] = s4;
        }
        #pragma unroll
        for (int it = 0; it < 8; ++it) {
            int jp = (t >> 4) + (it & 1) * 16;
            int dd = (t & 15) + (it >> 1) * 16;
            const float* vp = v + ((size_t)(b * S_LEN + j0 + jp * 2) * DIM + dd);
            float v0 = vp[0];
            float v1 = vp[DIM];
            unsigned int pk = (unsigned int)(unsigned short)f2bf(v0) |
                              ((unsigned int)(unsigned short)f2bf(v1) << 16);
            *(unsigned int*)&Vtlds[dd * KP + jp * 2] = pk;
        }
        __syncthreads();

        unsigned long long wbits[4];
        #pragma unroll
        for (int r = 0; r < 4; ++r)
            wbits[r] = Bits[(16 * wv + lg * 4 + r) * BP + kt];

        #pragma unroll
        for (int jt = 0; jt < 4; ++jt) {
            short8 b0 = *(short8*)&Klds[(jt * 16 + ll) * KP + lg * 8];
            short8 b1 = *(short8*)&Klds[(jt * 16 + ll) * KP + 32 + lg * 8];
            f32x4 c = {0.f, 0.f, 0.f, 0.f};
            c = __builtin_amdgcn_mfma_f32_16x16x32_bf16(qf[0], b0, c, 0, 0, 0);
            c = __builtin_amdgcn_mfma_f32_16x16x32_bf16(qf[1], b1, c, 0, 0, 0);
            #pragma unroll
            for (int r = 0; r < 4; ++r) {
                unsigned int bit = (unsigned int)(wbits[r] >> (jt * 16 + ll)) & 1u;
                float pexp = bit ? 0.f : __builtin_amdgcn_exp2f(c[r] * LOG2E_T);
                Albs[(16 * wv + lg * 4 + r) * AP + jt * 16 + ll] = pexp * inv[r];
            }
        }

        short8 paf[2];
        #pragma unroll
        for (int s = 0; s < 2; ++s) {
            const float* ap = &Albs[(16 * wv + ll) * AP + s * 32 + lg * 8];
            float4 x = *(const float4*)ap;
            float4 y = *(const float4*)(ap + 4);
            short8 f;
            f[0]=f2bf(x.x); f[1]=f2bf(x.y); f[2]=f2bf(x.z); f[3]=f2bf(x.w);
            f[4]=f2bf(y.x); f[5]=f2bf(y.y); f[6]=f2bf(y.z); f[7]=f2bf(y.w);
            paf[s] = f;
        }

        #pragma unroll
        for (int dt = 0; dt < 4; ++dt) {
            short8 b0 = *(short8*)&Vtlds[(dt * 16 + ll) * KP + lg * 8];
            short8 b1 = *(short8*)&Vtlds[(dt * 16 + ll) * KP + 32 + lg * 8];
            oacc[dt] = __builtin_amdgcn_mfma_f32_16x16x32_bf16(paf[0], b0, oacc[dt], 0, 0, 0);
            oacc[dt] = __builtin_amdgcn_mfma_f32_16x16x32_bf16(paf[1], b1, oacc[dt], 0, 0, 0);
        }

        {
            float* abase = attn + (size_t)b * S_LEN * S_LEN;
            #pragma unroll
            for (int ps = 0; ps < 4; ++ps) {
                int row = 16 * wv + lg + ps * 4;
                f32x4 val = *(f32x4*)&Albs[row * AP + ll * 4];
                float* dst = abase + (size_t)(i0 + row) * S_LEN + j0 + ll * 4;
                __builtin_nontemporal_store(val, (f32x4*)dst);
            }
        }
        __syncthreads();
    }

    #pragma unroll
    for (int dt = 0; dt < 4; ++dt)
        #pragma unroll
        for (int r = 0; r < 4; ++r)
            out[(size_t)(b * S_LEN + i0 + 16 * wv + lg * 4 + r) * DIM + dt * 16 + ll] = oacc[dt][r];
}

extern "C" void kernel_launch(void* const* d_in, const int* in_sizes, int n_in,
                              void* d_out, int out_size, void* d_ws, size_t ws_size,
                              hipStream_t stream) {
    const float* q    = (const float*)d_in[0];
    const float* k    = (const float*)d_in[1];
    const float* v    = (const float*)d_in[2];
    const int*   mask = (const int*)d_in[3];
    float* out  = (float*)d_out;
    float* attn = out + (size_t)NB * S_LEN * DIM;

    const size_t nel = (size_t)NB * S_LEN * DIM;       // 4.19M
    const size_t ws_needed = 2 * nel * sizeof(short);  // 16.8 MB

    if (ws_size >= ws_needed) {
        short* kbf = (short*)d_ws;
        short* vtb = kbf + nel;
        conv_k_kernel<<<dim3(nel / (256 * 8)), dim3(256), 0, stream>>>(k, kbf);
        conv_vt_kernel<<<dim3(NB * 32), dim3(256), 0, stream>>>(v, vtb);
        sdpa_v8<<<dim3(NB * (S_LEN / BR)), dim3(256), 0, stream>>>(q, mask, kbf, vtb, out, attn);
    } else {
        sdpa_fb<<<dim3(NB * (S_LEN / BR)), dim3(256), 0, stream>>>(q, k, v, mask, out, attn);
    }
}

// Round 9
// 277.964 us; speedup vs baseline: 1.2518x; 1.0981x over previous
//
#include <hip/hip_runtime.h>
#include <hip/hip_bf16.h>

typedef __attribute__((ext_vector_type(8))) short short8;
typedef __attribute__((ext_vector_type(4))) short short4b;
typedef __attribute__((ext_vector_type(4))) float f32x4;

#define S_LEN 2048
#define DIM   64
#define NB    32
#define BR    64
#define BC    64
#define NKT   (S_LEN / BC)   // 32

#define KP  72   // K/Vt row pitch in shorts (144B, 16B-aligned rows)
#define BP  33   // fallback bits row pitch in u64
#define AP  68   // attn-bounce row pitch in floats (272B, 16B-aligned)

__device__ __forceinline__ short f2bf(float f) {
    __hip_bfloat16 h = __float2bfloat16(f);
    return __builtin_bit_cast(short, h);
}

// raw barrier: NO implicit vmcnt/lgkm drain
__device__ __forceinline__ void barrier_raw() {
    __builtin_amdgcn_sched_barrier(0);
    __builtin_amdgcn_s_barrier();
    __builtin_amdgcn_sched_barrier(0);
}
// publish this wave's LDS writes, then barrier (still no vmcnt drain)
__device__ __forceinline__ void barrier_pub() {
    __builtin_amdgcn_sched_barrier(0);
    asm volatile("s_waitcnt lgkmcnt(0)" ::: "memory");
    __builtin_amdgcn_s_barrier();
    __builtin_amdgcn_sched_barrier(0);
}

// ============================ pre-pass kernels ============================

__global__ __launch_bounds__(256)
void conv_k_kernel(const float* __restrict__ k, short* __restrict__ kbf)
{
    size_t idx = ((size_t)blockIdx.x * 256 + threadIdx.x) * 8;
    const float* p = k + idx;
    float4 a = *(const float4*)p;
    float4 c = *(const float4*)(p + 4);
    short8 f;
    f[0]=f2bf(a.x); f[1]=f2bf(a.y); f[2]=f2bf(a.z); f[3]=f2bf(a.w);
    f[4]=f2bf(c.x); f[5]=f2bf(c.y); f[6]=f2bf(c.z); f[7]=f2bf(c.w);
    *(short8*)(kbf + idx) = f;
}

__global__ __launch_bounds__(256)
void conv_vt_kernel(const float* __restrict__ v, short* __restrict__ vtb)
{
    __shared__ float tile[64][65];
    const int t  = threadIdx.x;
    const int b  = blockIdx.x >> 5;
    const int j0 = (blockIdx.x & 31) * 64;

    #pragma unroll
    for (int p = 0; p < 4; ++p) {
        int j = (t >> 4) + p * 16;
        int d = (t & 15) * 4;
        float4 x = *(const float4*)(v + ((size_t)(b * S_LEN + j0 + j) * DIM + d));
        tile[j][d+0]=x.x; tile[j][d+1]=x.y; tile[j][d+2]=x.z; tile[j][d+3]=x.w;
    }
    __syncthreads();
    #pragma unroll
    for (int p = 0; p < 4; ++p) {
        int d  = (t >> 4) + p * 16;
        int j4 = (t & 15) * 4;
        short4b s4;
        s4[0]=f2bf(tile[j4+0][d]); s4[1]=f2bf(tile[j4+1][d]);
        s4[2]=f2bf(tile[j4+2][d]); s4[3]=f2bf(tile[j4+3][d]);
        *(short4b*)(vtb + ((size_t)(b * DIM + d) * S_LEN + j0 + j4)) = s4;
    }
}

// ============================ main kernel (R8 + 512B-burst streams) ============================

__global__ __launch_bounds__(256, 4)
void sdpa_v9(const float* __restrict__ q, const int* __restrict__ mask,
             const short* __restrict__ kbf, const short* __restrict__ vtb,
             float* __restrict__ out, float* __restrict__ attn)
{
    __shared__ __align__(16) short Klds[BR * KP];    // 9.2 KB
    __shared__ __align__(16) short Vtlds[DIM * KP];  // 9.2 KB
    __shared__ __align__(16) float Albs[BR * AP];    // 17.4 KB => 35.8 KB total

    const int t  = threadIdx.x;
    const int l  = t & 63;
    const int wv = t >> 6;
    const int lg = l >> 4;
    const int ll = l & 15;

    // XCD swizzle: batches 4x..4x+3 -> XCD x (K+Vt ~2MB fits its L2)
    const int bx  = blockIdx.x;
    const int kk  = bx >> 3;
    const int b   = (bx & 7) * 4 + (kk >> 5);
    const int i0  = (kk & 31) * BR;

    const float LOG2E_T = 0.18033688011112042f;   // log2(e)/8

    // staging map: thread t stages LDS row krow (16 shorts at kcol)
    const int krow = t >> 2;
    const int kcol = (t & 3) * 16;
    const size_t kgbase = (size_t)(b * S_LEN + krow) * DIM + kcol;        // + kt*BC*DIM
    const size_t vgbase = (size_t)(b * DIM + krow) * S_LEN + kcol;        // + kt*BC
    const size_t mbase  = (size_t)(b * S_LEN + i0 + 16 * wv) * S_LEN + l; // + r*S + s*128 + h*64

    // ---- Q fragments ----
    short8 qf[2];
    {
        const float* qrow = q + ((size_t)(b * S_LEN + i0 + 16 * wv + ll) * DIM);
        #pragma unroll
        for (int s = 0; s < 2; ++s) {
            const float* p = qrow + s * 32 + lg * 8;
            float4 a = *(const float4*)p;
            float4 c = *(const float4*)(p + 4);
            short8 f;
            f[0]=f2bf(a.x); f[1]=f2bf(a.y); f[2]=f2bf(a.z); f[3]=f2bf(a.w);
            f[4]=f2bf(c.x); f[5]=f2bf(c.y); f[6]=f2bf(c.z); f[7]=f2bf(c.w);
            qf[s] = f;
        }
    }

    // ---- prologue: K tile0 + mask super 0 (512B/row bursts) ----
    short8 kA0 = *(const short8*)(kbf + kgbase);
    short8 kA1 = *(const short8*)(kbf + kgbase + 8);
    short8 kB0, kB1;
    int m[32];
    #pragma unroll
    for (int r = 0; r < 16; ++r) {
        m[2*r+0] = __builtin_nontemporal_load(mask + mbase + (size_t)r * S_LEN);
        m[2*r+1] = __builtin_nontemporal_load(mask + mbase + (size_t)r * S_LEN + 64);
    }

    float rs[4] = {0.f, 0.f, 0.f, 0.f};
    unsigned long long w8[8];

    // ================= Phase 1: rowsums, mask bits -> registers =================
    for (int o = 0; o < 4; ++o) {
        #pragma unroll
        for (int ss = 0; ss < 4; ++ss) {
            const int kt0 = 8 * o + 2 * ss;
            const int sI  = 4 * o + ss;           // super index

            // ballots for both tiles of this super (loads issued 1 super ago)
            unsigned long long wb[2][4];
            #pragma unroll
            for (int r = 0; r < 16; ++r) {
                #pragma unroll
                for (int h = 0; h < 2; ++h) {
                    unsigned long long bal = __ballot(m[2*r+h] != 0);
                    if ((r >> 2) == lg) wb[h][r & 3] = bal;
                    if (lg == o && ll == r) w8[2*ss+h] = bal;
                }
            }

            // ---- inner h = 0 (tile kt0) ----
            barrier_raw();
            {
                short* kd = &Klds[krow * KP + kcol];
                *(short8*)kd = kA0;
                *(short8*)(kd + 8) = kA1;
            }
            barrier_pub();
            // issue K(kt0+1) and next mask super (512B/row) — in flight across compute
            {
                const short* kb = kbf + kgbase + (size_t)(kt0 + 1) * BC * DIM;
                kB0 = *(const short8*)kb;
                kB1 = *(const short8*)(kb + 8);
                const int sN = (sI < 15) ? sI + 1 : sI;
                const int* mp = mask + mbase + (size_t)sN * 128;
                #pragma unroll
                for (int r = 0; r < 16; ++r) {
                    m[2*r+0] = __builtin_nontemporal_load(mp + (size_t)r * S_LEN);
                    m[2*r+1] = __builtin_nontemporal_load(mp + (size_t)r * S_LEN + 64);
                }
            }
            __builtin_amdgcn_sched_barrier(0);
            #pragma unroll
            for (int jt = 0; jt < 4; ++jt) {
                short8 b0 = *(short8*)&Klds[(jt * 16 + ll) * KP + lg * 8];
                short8 b1 = *(short8*)&Klds[(jt * 16 + ll) * KP + 32 + lg * 8];
                f32x4 c = {0.f, 0.f, 0.f, 0.f};
                c = __builtin_amdgcn_mfma_f32_16x16x32_bf16(qf[0], b0, c, 0, 0, 0);
                c = __builtin_amdgcn_mfma_f32_16x16x32_bf16(qf[1], b1, c, 0, 0, 0);
                #pragma unroll
                for (int r = 0; r < 4; ++r) {
                    unsigned int bit = (unsigned int)(wb[0][r] >> (jt * 16 + ll)) & 1u;
                    rs[r] += bit ? 0.f : __builtin_amdgcn_exp2f(c[r] * LOG2E_T);
                }
            }

            // ---- inner h = 1 (tile kt0+1) ----
            barrier_raw();
            {
                short* kd = &Klds[krow * KP + kcol];
                *(short8*)kd = kB0;
                *(short8*)(kd + 8) = kB1;
            }
            barrier_pub();
            {
                const int ktn = (kt0 + 2 < NKT) ? kt0 + 2 : NKT - 1;
                const short* kb = kbf + kgbase + (size_t)ktn * BC * DIM;
                kA0 = *(const short8*)kb;
                kA1 = *(const short8*)(kb + 8);
            }
            __builtin_amdgcn_sched_barrier(0);
            #pragma unroll
            for (int jt = 0; jt < 4; ++jt) {
                short8 b0 = *(short8*)&Klds[(jt * 16 + ll) * KP + lg * 8];
                short8 b1 = *(short8*)&Klds[(jt * 16 + ll) * KP + 32 + lg * 8];
                f32x4 c = {0.f, 0.f, 0.f, 0.f};
                c = __builtin_amdgcn_mfma_f32_16x16x32_bf16(qf[0], b0, c, 0, 0, 0);
                c = __builtin_amdgcn_mfma_f32_16x16x32_bf16(qf[1], b1, c, 0, 0, 0);
                #pragma unroll
                for (int r = 0; r < 4; ++r) {
                    unsigned int bit = (unsigned int)(wb[1][r] >> (jt * 16 + ll)) & 1u;
                    rs[r] += bit ? 0.f : __builtin_amdgcn_exp2f(c[r] * LOG2E_T);
                }
            }
        }
    }

    // phase-2 tile-0 prefetch before the reduce (covers latency)
    kA0 = *(const short8*)(kbf + kgbase);
    kA1 = *(const short8*)(kbf + kgbase + 8);
    short8 vA0 = *(const short8*)(vtb + vgbase);
    short8 vA1 = *(const short8*)(vtb + vgbase + 8);
    short8 vB0, vB1;

    float inv[4];
    #pragma unroll
    for (int r = 0; r < 4; ++r) {
        float s = rs[r];
        s += __shfl_xor(s, 1);
        s += __shfl_xor(s, 2);
        s += __shfl_xor(s, 4);
        s += __shfl_xor(s, 8);
        inv[r] = 1.0f / s;
    }

    // ================= Phase 2: attn write (512B bursts) + PV =================
    f32x4 oacc[4];
    #pragma unroll
    for (int dt = 0; dt < 4; ++dt) oacc[dt] = (f32x4){0.f, 0.f, 0.f, 0.f};

    float* const abase = attn + (size_t)b * S_LEN * S_LEN;

    for (int o = 0; o < 4; ++o) {
        #pragma unroll
        for (int ss = 0; ss < 4; ++ss) {
            const int kt0 = 8 * o + 2 * ss;
            const int j0s = kt0 * BC;

            f32x4 pst[2][4];

            #pragma unroll
            for (int h = 0; h < 2; ++h) {
                barrier_raw();
                {
                    short* kd = &Klds[krow * KP + kcol];
                    *(short8*)kd = (h ? kB0 : kA0);
                    *(short8*)(kd + 8) = (h ? kB1 : kA1);
                    short* vd = &Vtlds[krow * KP + kcol];
                    *(short8*)vd = (h ? vB0 : vA0);
                    *(short8*)(vd + 8) = (h ? vB1 : vA1);
                }
                barrier_pub();
                if (h == 0) {
                    const short* kb = kbf + kgbase + (size_t)(kt0 + 1) * BC * DIM;
                    kB0 = *(const short8*)kb;
                    kB1 = *(const short8*)(kb + 8);
                    const short* vb = vtb + vgbase + (size_t)(kt0 + 1) * BC;
                    vB0 = *(const short8*)vb;
                    vB1 = *(const short8*)(vb + 8);
                } else {
                    const int ktn = (kt0 + 2 < NKT) ? kt0 + 2 : NKT - 1;
                    const short* kb = kbf + kgbase + (size_t)ktn * BC * DIM;
                    kA0 = *(const short8*)kb;
                    kA1 = *(const short8*)(kb + 8);
                    const short* vb = vtb + vgbase + (size_t)ktn * BC;
                    vA0 = *(const short8*)vb;
                    vA1 = *(const short8*)(vb + 8);
                }
                __builtin_amdgcn_sched_barrier(0);

                unsigned long long wb[4];
                #pragma unroll
                for (int r = 0; r < 4; ++r)
                    wb[r] = __shfl(w8[2*ss+h], 16 * o + lg * 4 + r);

                // QK^T -> normalized p -> Albs (wave-private rows)
                #pragma unroll
                for (int jt = 0; jt < 4; ++jt) {
                    short8 b0 = *(short8*)&Klds[(jt * 16 + ll) * KP + lg * 8];
                    short8 b1 = *(short8*)&Klds[(jt * 16 + ll) * KP + 32 + lg * 8];
                    f32x4 c = {0.f, 0.f, 0.f, 0.f};
                    c = __builtin_amdgcn_mfma_f32_16x16x32_bf16(qf[0], b0, c, 0, 0, 0);
                    c = __builtin_amdgcn_mfma_f32_16x16x32_bf16(qf[1], b1, c, 0, 0, 0);
                    #pragma unroll
                    for (int r = 0; r < 4; ++r) {
                        unsigned int bit = (unsigned int)(wb[r] >> (jt * 16 + ll)) & 1u;
                        float pexp = bit ? 0.f : __builtin_amdgcn_exp2f(c[r] * LOG2E_T);
                        Albs[(16 * wv + lg * 4 + r) * AP + jt * 16 + ll] = pexp * inv[r];
                    }
                }

                // PV A-fragments from wave-private bounce (transpose for free)
                short8 paf[2];
                #pragma unroll
                for (int s = 0; s < 2; ++s) {
                    const float* ap = &Albs[(16 * wv + ll) * AP + s * 32 + lg * 8];
                    float4 x = *(const float4*)ap;
                    float4 y = *(const float4*)(ap + 4);
                    short8 f;
                    f[0]=f2bf(x.x); f[1]=f2bf(x.y); f[2]=f2bf(x.z); f[3]=f2bf(x.w);
                    f[4]=f2bf(y.x); f[5]=f2bf(y.y); f[6]=f2bf(y.z); f[7]=f2bf(y.w);
                    paf[s] = f;
                }

                #pragma unroll
                for (int dt = 0; dt < 4; ++dt) {
                    short8 b0 = *(short8*)&Vtlds[(dt * 16 + ll) * KP + lg * 8];
                    short8 b1 = *(short8*)&Vtlds[(dt * 16 + ll) * KP + 32 + lg * 8];
                    oacc[dt] = __builtin_amdgcn_mfma_f32_16x16x32_bf16(paf[0], b0, oacc[dt], 0, 0, 0);
                    oacc[dt] = __builtin_amdgcn_mfma_f32_16x16x32_bf16(paf[1], b1, oacc[dt], 0, 0, 0);
                }

                // hold this tile's store data in registers
                #pragma unroll
                for (int ps = 0; ps < 4; ++ps) {
                    int row = 16 * wv + lg + ps * 4;
                    pst[h][ps] = *(f32x4*)&Albs[row * AP + ll * 4];
                }
            }

            // 512B-burst attn stores: per row, two adjacent 256B chunks
            #pragma unroll
            for (int ps = 0; ps < 4; ++ps) {
                int row = 16 * wv + lg + ps * 4;
                float* dst = abase + (size_t)(i0 + row) * S_LEN + j0s + ll * 4;
                __builtin_nontemporal_store(pst[0][ps], (f32x4*)dst);
                __builtin_nontemporal_store(pst[1][ps], (f32x4*)(dst + BC));
            }
        }
    }

    #pragma unroll
    for (int dt = 0; dt < 4; ++dt)
        #pragma unroll
        for (int r = 0; r < 4; ++r)
            out[(size_t)(b * S_LEN + i0 + 16 * wv + lg * 4 + r) * DIM + dt * 16 + ll] = oacc[dt][r];
}

// ============================ fallback (proven R2 kernel) ============================

__global__ __launch_bounds__(256, 3)
void sdpa_fb(const float* __restrict__ q, const float* __restrict__ k,
             const float* __restrict__ v, const int* __restrict__ mask,
             float* __restrict__ out, float* __restrict__ attn)
{
    __shared__ __align__(16) short Klds[BR * KP];
    __shared__ __align__(16) short Vtlds[DIM * KP];
    __shared__ __align__(16) unsigned long long Bits[BR * BP];
    __shared__ __align__(16) float Albs[BR * AP];

    const int t  = threadIdx.x;
    const int l  = t & 63;
    const int wv = t >> 6;
    const int lg = l >> 4;
    const int ll = l & 15;

    const int wg = blockIdx.x;
    const int b  = wg >> 5;
    const int i0 = (wg & 31) * BR;

    const float LOG2E_T = 0.18033688011112042f;

    short8 qf[2];
    {
        const float* qrow = q + ((size_t)(b * S_LEN + i0 + 16 * wv + ll) * DIM);
        #pragma unroll
        for (int s = 0; s < 2; ++s) {
            const float* p = qrow + s * 32 + lg * 8;
            float4 a = *(const float4*)p;
            float4 c = *(const float4*)(p + 4);
            short8 f;
            f[0]=f2bf(a.x); f[1]=f2bf(a.y); f[2]=f2bf(a.z); f[3]=f2bf(a.w);
            f[4]=f2bf(c.x); f[5]=f2bf(c.y); f[6]=f2bf(c.z); f[7]=f2bf(c.w);
            qf[s] = f;
        }
    }

    float rs[4] = {0.f, 0.f, 0.f, 0.f};

    for (int kt = 0; kt < NKT; ++kt) {
        const int j0 = kt * BC;
        #pragma unroll
        for (int p = 0; p < 4; ++p) {
            int row = (t >> 4) + p * 16;
            int dd  = (t & 15) * 4;
            float4 kv4 = *(const float4*)(k + ((size_t)(b * S_LEN + j0 + row) * DIM + dd));
            short4b s4;
            s4[0]=f2bf(kv4.x); s4[1]=f2bf(kv4.y); s4[2]=f2bf(kv4.z); s4[3]=f2bf(kv4.w);
            *(short4b*)&Klds[row * KP + dd] = s4;
        }
        {
            const int* mrow = mask + (size_t)(b * S_LEN + i0 + 16 * wv) * S_LEN + j0 + l;
            int mv[16];
            #pragma unroll
            for (int r = 0; r < 16; ++r)
                mv[r] = __builtin_nontemporal_load(mrow + (size_t)r * S_LEN);
            unsigned long long myword = 0ull;
            #pragma unroll
            for (int r = 0; r < 16; ++r) {
                unsigned long long bal = __ballot(mv[r] != 0);
                if (ll == r) myword = bal;
            }
            if (l < 16) Bits[(16 * wv + l) * BP + kt] = myword;
        }
        __syncthreads();

        unsigned long long wbits[4];
        #pragma unroll
        for (int r = 0; r < 4; ++r)
            wbits[r] = Bits[(16 * wv + lg * 4 + r) * BP + kt];

        #pragma unroll
        for (int jt = 0; jt < 4; ++jt) {
            short8 b0 = *(short8*)&Klds[(jt * 16 + ll) * KP + lg * 8];
            short8 b1 = *(short8*)&Klds[(jt * 16 + ll) * KP + 32 + lg * 8];
            f32x4 c = {0.f, 0.f, 0.f, 0.f};
            c = __builtin_amdgcn_mfma_f32_16x16x32_bf16(qf[0], b0, c, 0, 0, 0);
            c = __builtin_amdgcn_mfma_f32_16x16x32_bf16(qf[1], b1, c, 0, 0, 0);
            #pragma unroll
            for (int r = 0; r < 4; ++r) {
                unsigned int bit = (unsigned int)(wbits[r] >> (jt * 16 + ll)) & 1u;
                rs[r] += bit ? 0.f : __builtin_amdgcn_exp2f(c[r] * LOG2E_T);
            }
        }
        __syncthreads();
    }

    float inv[4];
    #pragma unroll
    for (int r = 0; r < 4; ++r) {
        float s = rs[r];
        s += __shfl_xor(s, 1);
        s += __shfl_xor(s, 2);
        s += __shfl_xor(s, 4);
        s += __shfl_xor(s, 8);
        inv[r] = 1.0f / s;
    }

    f32x4 oacc[4];
    #pragma unroll
    for (int dt = 0; dt < 4; ++dt) oacc[dt] = (f32x4){0.f, 0.f, 0.f, 0.f};

    for (int kt = 0; kt < NKT; ++kt) {
        const int j0 = kt * BC;
        #pragma unroll
        for (int p = 0; p < 4; ++p) {
            int row = (t >> 4) + p * 16;
            int dd  = (t & 15) * 4;
            float4 kv4 = *(const float4*)(k + ((size_t)(b * S_LEN + j0 + row) * DIM + dd));
            short4b s4;
            s4[0]=f2bf(kv4.x); s4[1]=f2bf(kv4.y); s4[2]=f2bf(kv4.z); s4[3]=f2bf(kv4.w);
            *(short4b*)&Klds[row * KP + dd] = s4;
        }
        #pragma unroll
        for (int it = 0; it < 8; ++it) {
            int jp = (t >> 4) + (it & 1) * 16;
            int dd = (t & 15) + (it >> 1) * 16;
            const float* vp = v + ((size_t)(b * S_LEN + j0 + jp * 2) * DIM + dd);
            float v0 = vp[0];
            float v1 = vp[DIM];
            unsigned int pk = (unsigned int)(unsigned short)f2bf(v0) |
                              ((unsigned int)(unsigned short)f2bf(v1) << 16);
            *(unsigned int*)&Vtlds[dd * KP + jp * 2] = pk;
        }
        __syncthreads();

        unsigned long long wbits[4];
        #pragma unroll
        for (int r = 0; r < 4; ++r)
            wbits[r] = Bits[(16 * wv + lg * 4 + r) * BP + kt];

        #pragma unroll
        for (int jt = 0; jt < 4; ++jt) {
            short8 b0 = *(short8*)&Klds[(jt * 16 + ll) * KP + lg * 8];
            short8 b1 = *(short8*)&Klds[(jt * 16 + ll) * KP + 32 + lg * 8];
            f32x4 c = {0.f, 0.f, 0.f, 0.f};
            c = __builtin_amdgcn_mfma_f32_16x16x32_bf16(qf[0], b0, c, 0, 0, 0);
            c = __builtin_amdgcn_mfma_f32_16x16x32_bf16(qf[1], b1, c, 0, 0, 0);
            #pragma unroll
            for (int r = 0; r < 4; ++r) {
                unsigned int bit = (unsigned int)(wbits[r] >> (jt * 16 + ll)) & 1u;
                float pexp = bit ? 0.f : __builtin_amdgcn_exp2f(c[r] * LOG2E_T);
                Albs[(16 * wv + lg * 4 + r) * AP + jt * 16 + ll] = pexp * inv[r];
            }
        }

        short8 paf[2];
        #pragma unroll
        for (int s = 0; s < 2; ++s) {
            const float* ap = &Albs[(16 * wv + ll) * AP + s * 32 + lg * 8];
            float4 x = *(const float4*)ap;
            float4 y = *(const float4*)(ap + 4);
            short8 f;
            f[0]=f2bf(x.x); f[1]=f2bf(x.y); f[2]=f2bf(x.z); f[3]=f2bf(x.w);
            f[4]=f2bf(y.x); f[5]=f2bf(y.y); f[6]=f2bf(y.z); f[7]=f2bf(y.w);
            paf[s] = f;
        }

        #pragma unroll
        for (int dt = 0; dt < 4; ++dt) {
            short8 b0 = *(short8*)&Vtlds[(dt * 16 + ll) * KP + lg * 8];
            short8 b1 = *(short8*)&Vtlds[(dt * 16 + ll) * KP + 32 + lg * 8];
            oacc[dt] = __builtin_amdgcn_mfma_f32_16x16x32_bf16(paf[0], b0, oacc[dt], 0, 0, 0);
            oacc[dt] = __builtin_amdgcn_mfma_f32_16x16x32_bf16(paf[1], b1, oacc[dt], 0, 0, 0);
        }

        {
            float* abase = attn + (size_t)b * S_LEN * S_LEN;
            #pragma unroll
            for (int ps = 0; ps < 4; ++ps) {
                int row = 16 * wv + lg + ps * 4;
                f32x4 val = *(f32x4*)&Albs[row * AP + ll * 4];
                float* dst = abase + (size_t)(i0 + row) * S_LEN + j0 + ll * 4;
                __builtin_nontemporal_store(val, (f32x4*)dst);
            }
        }
        __syncthreads();
    }

    #pragma unroll
    for (int dt = 0; dt < 4; ++dt)
        #pragma unroll
        for (int r = 0; r < 4; ++r)
            out[(size_t)(b * S_LEN + i0 + 16 * wv + lg * 4 + r) * DIM + dt * 16 + ll] = oacc[dt][r];
}

extern "C" void kernel_launch(void* const* d_in, const int* in_sizes, int n_in,
                              void* d_out, int out_size, void* d_ws, size_t ws_size,
                              hipStream_t stream) {
    const float* q    = (const float*)d_in[0];
    const float* k    = (const float*)d_in[1];
    const float* v    = (const float*)d_in[2];
    const int*   mask = (const int*)d_in[3];
    float* out  = (float*)d_out;
    float* attn = out + (size_t)NB * S_LEN * DIM;

    const size_t nel = (size_t)NB * S_LEN * DIM;       // 4.19M
    const size_t ws_needed = 2 * nel * sizeof(short);  // 16.8 MB

    if (ws_size >= ws_needed) {
        short* kbf = (short*)d_ws;
        short* vtb = kbf + nel;
        conv_k_kernel<<<dim3(nel / (256 * 8)), dim3(256), 0, stream>>>(k, kbf);
        conv_vt_kernel<<<dim3(NB * 32), dim3(256), 0, stream>>>(v, vtb);
        sdpa_v9<<<dim3(NB * (S_LEN / BR)), dim3(256), 0, stream>>>(q, mask, kbf, vtb, out, attn);
    } else {
        sdpa_fb<<<dim3(NB * (S_LEN / BR)), dim3(256), 0, stream>>>(q, k, v, mask, out, attn);
    }
}